// Round 1
// baseline (265.988 us; speedup 1.0000x reference)
//
#include <hip/hip_runtime.h>
#include <stdint.h>
#include <math.h>

#define C_NUM 2048
#define N_TOT 4096
#define B_TOT 4096
#define KNOWN 1024

typedef __attribute__((ext_vector_type(8))) short short8;
typedef __attribute__((ext_vector_type(4))) float f32x4;

__device__ __forceinline__ unsigned short f2bf(float x) {
  unsigned u = __float_as_uint(x);
  unsigned r = (u + 0x7fffu + ((u >> 16) & 1u)) >> 16;
  return (unsigned short)r;
}

__device__ __forceinline__ void gld16(const void* g, void* l) {
  __builtin_amdgcn_global_load_lds(
      (const __attribute__((address_space(1))) void*)g,
      (__attribute__((address_space(3))) void*)l, 16, 0, 0);
}

// ---------------- Kernel 1: column sums and squared norms ----------------
// c in [0,4096): c<2048 -> prob col c ; else prob_s col c-2048
__global__ void colstats_kernel(const float* __restrict__ prob,
                                const float* __restrict__ prob_s,
                                float* __restrict__ colsum,
                                float* __restrict__ norm2) {
  int c = blockIdx.x * 256 + threadIdx.x;   // 0..4095
  int b0 = blockIdx.y * 128;
  const float* src = (c < C_NUM) ? prob : prob_s;
  int col = c & (C_NUM - 1);
  float s = 0.f, s2 = 0.f;
  for (int r = 0; r < 128; ++r) {
    float v = src[(size_t)(b0 + r) * C_NUM + col];
    s += v;
    s2 += v * v;
  }
  atomicAdd(&colsum[c], s);
  atomicAdd(&norm2[c], s2);
}

// ---------------- Kernel 2: transpose + normalize -> bf16 Pn[4096][4096] --
// Pn[i][b] = P[i][b]/max(||P_i||,eps), P[i][b] = (i<C? prob[b][i] : prob_s[b][i-C])
__global__ void transpose_norm_kernel(const float* __restrict__ prob,
                                      const float* __restrict__ prob_s,
                                      const float* __restrict__ norm2,
                                      unsigned short* __restrict__ Pn) {
  __shared__ float tile[64][65];
  int tx = threadIdx.x;          // 0..63
  int ty = threadIdx.y;          // 0..3
  int c0 = blockIdx.x * 64;      // class (column-of-input) tile
  int b0 = blockIdx.y * 64;      // batch tile
  const float* src = (c0 < C_NUM) ? prob : prob_s;
  int colbase = (c0 & (C_NUM - 1)) + tx;
#pragma unroll
  for (int r = 0; r < 16; ++r) {
    int b = b0 + r * 4 + ty;
    tile[r * 4 + ty][tx] = src[(size_t)b * C_NUM + colbase];
  }
  __syncthreads();
#pragma unroll
  for (int r = 0; r < 16; ++r) {
    int i = c0 + r * 4 + ty;
    float inv = 1.0f / fmaxf(sqrtf(norm2[i]), 1e-8f);
    float v = tile[tx][r * 4 + ty] * inv;
    Pn[(size_t)i * B_TOT + b0 + tx] = f2bf(v);
  }
}

// ---------------- Kernel 3: fused GEMM (sim = Pn Pn^T / TEMP) + epilogue --
// 128x128 tile, 4 waves (2x2), each wave 64x64 via 4x4 fragments of
// mfma_f32_16x16x32_bf16. Double-buffered LDS staged via global_load_lds.
__global__ __launch_bounds__(256) void simgemm_kernel(
    const unsigned short* __restrict__ Pn,
    float* __restrict__ sumexp,
    float* __restrict__ pos) {
  __shared__ unsigned short As[2][128 * 32];
  __shared__ unsigned short Bs[2][128 * 32];

  const int tid = threadIdx.x;
  const int l = tid & 63;
  const int w = tid >> 6;            // wave 0..3
  const int wr = w >> 1, wc = w & 1; // 2x2 wave grid
  const int ib = blockIdx.y * 128;
  const int jb = blockIdx.x * 128;

  // staging: chunk c = q*4 + w (q in {0,1}); lane l covers 16B at
  // LDS linear offset c*1024 + l*16  -> row = c*16 + (l>>2), kbyte=(l&3)*16
  const int srow = (l >> 2);
  const int skb = (l & 3) * 16;
  const char* gA0 = (const char*)Pn + (size_t)(ib + w * 16 + srow) * (B_TOT * 2) + skb;
  const char* gA1 = gA0 + (size_t)64 * (B_TOT * 2);
  const char* gB0 = (const char*)Pn + (size_t)(jb + w * 16 + srow) * (B_TOT * 2) + skb;
  const char* gB1 = gB0 + (size_t)64 * (B_TOT * 2);
  const int ldsOfA = w * 1024;

  f32x4 acc[4][4];
#pragma unroll
  for (int a = 0; a < 4; ++a)
#pragma unroll
    for (int b = 0; b < 4; ++b)
      acc[a][b] = (f32x4){0.f, 0.f, 0.f, 0.f};

  // fragment read geometry
  const int arow = wr * 64 + (l & 15);
  const int brow = wc * 64 + (l & 15);
  const int kb = (l >> 4) * 16;   // byte offset within 64B LDS row

#define STAGE(buf, kofs)                                                    \
  do {                                                                      \
    gld16(gA0 + (kofs), (char*)&As[buf][0] + ldsOfA);                       \
    gld16(gA1 + (kofs), (char*)&As[buf][0] + ldsOfA + 4096);                \
    gld16(gB0 + (kofs), (char*)&Bs[buf][0] + ldsOfA);                       \
    gld16(gB1 + (kofs), (char*)&Bs[buf][0] + ldsOfA + 4096);                \
  } while (0)

  STAGE(0, 0);
  __syncthreads();   // compiler drains vmcnt before s_barrier

  int cur = 0;
  const int NT = B_TOT / 32;   // 128 K-tiles
  for (int kt = 0; kt < NT; ++kt) {
    if (kt + 1 < NT) STAGE(cur ^ 1, (size_t)(kt + 1) * 64);

    short8 af[4], bf[4];
#pragma unroll
    for (int f = 0; f < 4; ++f)
      af[f] = *(const short8*)((const char*)&As[cur][0] + (arow + f * 16) * 64 + kb);
#pragma unroll
    for (int f = 0; f < 4; ++f)
      bf[f] = *(const short8*)((const char*)&Bs[cur][0] + (brow + f * 16) * 64 + kb);

#pragma unroll
    for (int fm = 0; fm < 4; ++fm)
#pragma unroll
      for (int fn = 0; fn < 4; ++fn)
        acc[fm][fn] = __builtin_amdgcn_mfma_f32_16x16x32_bf16(
            af[fm], bf[fn], acc[fm][fn], 0, 0, 0);

    __syncthreads();   // drains vmcnt+lgkmcnt: staging of next, reads of cur
    cur ^= 1;
  }
#undef STAGE

  // epilogue: v = 2*dot ; skip diag; j==i^2048 is the positive (store pos);
  // masked rows ((i&1024)==0): j<1024 contributes 1.0 ; else exp(v).
#pragma unroll
  for (int fm = 0; fm < 4; ++fm) {
#pragma unroll
    for (int r = 0; r < 4; ++r) {
      const int i = ib + wr * 64 + fm * 16 + (l >> 4) * 4 + r;
      float rs = 0.f;
#pragma unroll
      for (int fn = 0; fn < 4; ++fn) {
        const int j = jb + wc * 64 + fn * 16 + (l & 15);
        float v = acc[fm][fn][r] * 2.0f;   // /TEMP (=0.5)
        if (j == (i ^ 2048)) pos[i] = v;   // unique writer
        float contrib = 0.f;
        if (j != i && j != (i ^ 2048))
          contrib = (((i & 1024) == 0) && (j < KNOWN)) ? 1.0f : __expf(v);
        rs += contrib;
      }
      // reduce across the 16 lanes sharing this row (bits 0..3 of lane id)
      rs += __shfl_xor(rs, 1);
      rs += __shfl_xor(rs, 2);
      rs += __shfl_xor(rs, 4);
      rs += __shfl_xor(rs, 8);
      if ((l & 15) == 0) atomicAdd(&sumexp[i], rs);
    }
  }
}

// ---------------- Kernel 4: finalize ----------------
__device__ float block_reduce_256(float v, volatile float* red) {
#pragma unroll
  for (int m = 32; m >= 1; m >>= 1) v += __shfl_xor(v, m);
  __syncthreads();
  if ((threadIdx.x & 63) == 0) red[threadIdx.x >> 6] = v;
  __syncthreads();
  return red[0] + red[1] + red[2] + red[3];
}

__global__ void finalize_kernel(const float* __restrict__ colsum,
                                const float* __restrict__ sumexp,
                                const float* __restrict__ pos,
                                float* __restrict__ out) {
  __shared__ float red[4];
  int t = threadIdx.x;
  float ce = 0.f, t1 = 0.f, t2 = 0.f;
  for (int i = t; i < N_TOT; i += 256) ce += logf(sumexp[i]) - pos[i];
  for (int c = t; c < C_NUM; c += 256) t1 += colsum[c];
  for (int c = t; c < C_NUM; c += 256) t2 += colsum[C_NUM + c];
  ce = block_reduce_256(ce, red);
  t1 = block_reduce_256(t1, red);
  t2 = block_reduce_256(t2, red);
  float e1 = 0.f, e2 = 0.f;
  for (int c = t; c < C_NUM; c += 256) {
    float m = colsum[c] / t1;
    e1 += m * logf(m);
  }
  for (int c = t; c < C_NUM; c += 256) {
    float m = colsum[C_NUM + c] / t2;
    e2 += m * logf(m);
  }
  e1 = block_reduce_256(e1, red);
  e2 = block_reduce_256(e2, red);
  if (t == 0) {
    float reg = logf((float)C_NUM) + e1 + logf((float)C_NUM) + e2;
    out[0] = ce / (float)N_TOT + reg;
  }
}

extern "C" void kernel_launch(void* const* d_in, const int* in_sizes, int n_in,
                              void* d_out, int out_size, void* d_ws, size_t ws_size,
                              hipStream_t stream) {
  const float* prob = (const float*)d_in[0];
  const float* prob_s = (const float*)d_in[1];
  float* out = (float*)d_out;

  char* ws = (char*)d_ws;
  unsigned short* Pn = (unsigned short*)ws;                     // 32 MB bf16
  float* norm2 = (float*)(ws + (size_t)N_TOT * B_TOT * 2);      // 4096 f32
  float* colsum = norm2 + N_TOT;                                // 4096 f32
  float* sumexp = colsum + N_TOT;                               // 4096 f32
  float* pos = sumexp + N_TOT;                                  // 4096 f32

  // zero the atomic accumulators (norm2, colsum, sumexp are contiguous)
  hipMemsetAsync(norm2, 0, (size_t)3 * N_TOT * sizeof(float), stream);

  colstats_kernel<<<dim3(16, 32), 256, 0, stream>>>(prob, prob_s, colsum, norm2);
  transpose_norm_kernel<<<dim3(64, 64), dim3(64, 4), 0, stream>>>(prob, prob_s, norm2, Pn);
  simgemm_kernel<<<dim3(32, 32), 256, 0, stream>>>(Pn, sumexp, pos);
  finalize_kernel<<<1, 256, 0, stream>>>(colsum, sumexp, pos, out);
}

// Round 2
// 240.366 us; speedup vs baseline: 1.1066x; 1.1066x over previous
//
#include <hip/hip_runtime.h>
#include <stdint.h>
#include <math.h>

#define C_NUM 2048
#define N_TOT 4096
#define B_TOT 4096
#define KNOWN 1024

typedef __attribute__((ext_vector_type(8))) short short8;
typedef __attribute__((ext_vector_type(4))) float f32x4;

__device__ __forceinline__ unsigned short f2bf(float x) {
  unsigned u = __float_as_uint(x);
  unsigned r = (u + 0x7fffu + ((u >> 16) & 1u)) >> 16;
  return (unsigned short)r;
}

__device__ __forceinline__ void gld16(const void* g, void* l) {
  __builtin_amdgcn_global_load_lds(
      (const __attribute__((address_space(1))) void*)g,
      (__attribute__((address_space(3))) void*)l, 16, 0, 0);
}

// ---- Kernel 1: transpose + bf16 convert + colsum/norm2 partials ----------
// Pn[i][b] = bf16(P[i][b]) UNNORMALIZED; normalization folded into epilogue.
// Each input element visited exactly once -> per-thread partial sums.
__global__ void transpose_stats_kernel(const float* __restrict__ prob,
                                       const float* __restrict__ prob_s,
                                       float* __restrict__ colsum,
                                       float* __restrict__ norm2,
                                       unsigned short* __restrict__ Pn) {
  __shared__ float tile[64][65];
  int tx = threadIdx.x;          // 0..63
  int ty = threadIdx.y;          // 0..3
  int c0 = blockIdx.x * 64;      // class tile (0..4095)
  int b0 = blockIdx.y * 64;      // batch tile
  const float* src = (c0 < C_NUM) ? prob : prob_s;
  int colbase = (c0 & (C_NUM - 1)) + tx;
  float s = 0.f, s2 = 0.f;
#pragma unroll
  for (int r = 0; r < 16; ++r) {
    int b = b0 + r * 4 + ty;
    float v = src[(size_t)b * C_NUM + colbase];
    tile[r * 4 + ty][tx] = v;
    s += v;
    s2 += v * v;
  }
  atomicAdd(&colsum[c0 + tx], s);
  atomicAdd(&norm2[c0 + tx], s2);
  __syncthreads();
#pragma unroll
  for (int r = 0; r < 16; ++r) {
    int i = c0 + r * 4 + ty;
    Pn[(size_t)i * B_TOT + b0 + tx] = f2bf(tile[tx][r * 4 + ty]);
  }
}

// ---- Kernel 2: invn[i] = 1/max(||P_i||, eps) ------------------------------
__global__ void invnorm_kernel(const float* __restrict__ norm2,
                               float* __restrict__ invn) {
  int i = blockIdx.x * 256 + threadIdx.x;
  invn[i] = 1.0f / fmaxf(sqrtf(norm2[i]), 1e-8f);
}

// ---- Kernel 3: symmetric fused GEMM + softmax-denominator epilogue -------
// Only upper-triangular tile pairs (jt >= it). Off-diagonal blocks feed both
// row i and row j denominators (sim is symmetric). 128x128 tile, 4 waves.
__global__ __launch_bounds__(256) void simgemm_kernel(
    const unsigned short* __restrict__ Pn,
    const float* __restrict__ invn,
    float* __restrict__ sumexp,
    float* __restrict__ pos) {
  __shared__ unsigned short As[2][128 * 32];
  __shared__ unsigned short Bs[2][128 * 32];

  const int tid = threadIdx.x;
  const int l = tid & 63;
  const int w = tid >> 6;            // wave 0..3
  const int wr = w >> 1, wc = w & 1; // 2x2 wave grid

  // triangular decode: block t -> (it, jt) with jt >= it, 32x32 tile grid
  int t = blockIdx.x;
  int it = 0, rem = 32;
  while (t >= rem) { t -= rem; ++it; --rem; }
  const int jt = it + t;
  const int ib = it * 128;
  const int jb = jt * 128;
  const bool diag = (it == jt);

  const int srow = (l >> 2);
  const int skb = (l & 3) * 16;
  const char* gA0 = (const char*)Pn + (size_t)(ib + w * 16 + srow) * (B_TOT * 2) + skb;
  const char* gA1 = gA0 + (size_t)64 * (B_TOT * 2);
  const char* gB0 = (const char*)Pn + (size_t)(jb + w * 16 + srow) * (B_TOT * 2) + skb;
  const char* gB1 = gB0 + (size_t)64 * (B_TOT * 2);
  const int ldsOfA = w * 1024;

  f32x4 acc[4][4];
#pragma unroll
  for (int a = 0; a < 4; ++a)
#pragma unroll
    for (int b = 0; b < 4; ++b)
      acc[a][b] = (f32x4){0.f, 0.f, 0.f, 0.f};

  const int arow = wr * 64 + (l & 15);
  const int brow = wc * 64 + (l & 15);
  const int kb = (l >> 4) * 16;

#define STAGE(buf, kofs)                                                    \
  do {                                                                      \
    gld16(gA0 + (kofs), (char*)&As[buf][0] + ldsOfA);                       \
    gld16(gA1 + (kofs), (char*)&As[buf][0] + ldsOfA + 4096);                \
    gld16(gB0 + (kofs), (char*)&Bs[buf][0] + ldsOfA);                       \
    gld16(gB1 + (kofs), (char*)&Bs[buf][0] + ldsOfA + 4096);                \
  } while (0)

  STAGE(0, 0);
  __syncthreads();

  int cur = 0;
  const int NT = B_TOT / 32;
  for (int kt = 0; kt < NT; ++kt) {
    if (kt + 1 < NT) STAGE(cur ^ 1, (size_t)(kt + 1) * 64);

    short8 af[4], bf[4];
#pragma unroll
    for (int f = 0; f < 4; ++f)
      af[f] = *(const short8*)((const char*)&As[cur][0] + (arow + f * 16) * 64 + kb);
#pragma unroll
    for (int f = 0; f < 4; ++f)
      bf[f] = *(const short8*)((const char*)&Bs[cur][0] + (brow + f * 16) * 64 + kb);

#pragma unroll
    for (int fm = 0; fm < 4; ++fm)
#pragma unroll
      for (int fn = 0; fn < 4; ++fn)
        acc[fm][fn] = __builtin_amdgcn_mfma_f32_16x16x32_bf16(
            af[fm], bf[fn], acc[fm][fn], 0, 0, 0);

    __syncthreads();
    cur ^= 1;
  }
#undef STAGE

  // epilogue. v = 2 * dot * invn[i] * invn[j]
  float invj[4];
#pragma unroll
  for (int fn = 0; fn < 4; ++fn)
    invj[fn] = invn[jb + wc * 64 + fn * 16 + (l & 15)];

  if (diag) {
#pragma unroll
    for (int fm = 0; fm < 4; ++fm) {
#pragma unroll
      for (int r = 0; r < 4; ++r) {
        const int i = ib + wr * 64 + fm * 16 + (l >> 4) * 4 + r;
        const float invi = invn[i];
        float rs = 0.f;
#pragma unroll
        for (int fn = 0; fn < 4; ++fn) {
          const int j = jb + wc * 64 + fn * 16 + (l & 15);
          float v = acc[fm][fn][r] * 2.0f * invi * invj[fn];
          if (j != i)   // i^2048 can't occur inside a diagonal block
            rs += (((i & 1024) == 0) && (j < KNOWN)) ? 1.0f : __expf(v);
        }
        rs += __shfl_xor(rs, 1);
        rs += __shfl_xor(rs, 2);
        rs += __shfl_xor(rs, 4);
        rs += __shfl_xor(rs, 8);
        if ((l & 15) == 0) atomicAdd(&sumexp[i], rs);
      }
    }
  } else {
    float cs[4] = {0.f, 0.f, 0.f, 0.f};   // per-fn contribution to row j
#pragma unroll
    for (int fm = 0; fm < 4; ++fm) {
#pragma unroll
      for (int r = 0; r < 4; ++r) {
        const int i = ib + wr * 64 + fm * 16 + (l >> 4) * 4 + r;
        const float invi = invn[i];
        float rs = 0.f;
#pragma unroll
        for (int fn = 0; fn < 4; ++fn) {
          const int j = jb + wc * 64 + fn * 16 + (l & 15);
          float v = acc[fm][fn][r] * 2.0f * invi * invj[fn];
          if (j == (i ^ 2048)) {
            pos[i] = v;          // symmetric entry has the same value
            pos[j] = v;
          } else {               // j != i always holds off-diagonal
            float e = __expf(v);
            rs += (((i & 1024) == 0) && (j < KNOWN)) ? 1.0f : e;
            cs[fn] += (((j & 1024) == 0) && (i < KNOWN)) ? 1.0f : e;
          }
        }
        rs += __shfl_xor(rs, 1);
        rs += __shfl_xor(rs, 2);
        rs += __shfl_xor(rs, 4);
        rs += __shfl_xor(rs, 8);
        if ((l & 15) == 0) atomicAdd(&sumexp[i], rs);
      }
    }
#pragma unroll
    for (int fn = 0; fn < 4; ++fn) {
      cs[fn] += __shfl_xor(cs[fn], 16);
      cs[fn] += __shfl_xor(cs[fn], 32);
    }
    if (l < 16) {
#pragma unroll
      for (int fn = 0; fn < 4; ++fn)
        atomicAdd(&sumexp[jb + wc * 64 + fn * 16 + l], cs[fn]);
    }
  }
}

// ---- Kernel 4: finalize ---------------------------------------------------
__device__ float block_reduce_256(float v, volatile float* red) {
#pragma unroll
  for (int m = 32; m >= 1; m >>= 1) v += __shfl_xor(v, m);
  __syncthreads();
  if ((threadIdx.x & 63) == 0) red[threadIdx.x >> 6] = v;
  __syncthreads();
  return red[0] + red[1] + red[2] + red[3];
}

__global__ void finalize_kernel(const float* __restrict__ colsum,
                                const float* __restrict__ sumexp,
                                const float* __restrict__ pos,
                                float* __restrict__ out) {
  __shared__ float red[4];
  int t = threadIdx.x;
  float ce = 0.f, t1 = 0.f, t2 = 0.f;
  for (int i = t; i < N_TOT; i += 256) ce += logf(sumexp[i]) - pos[i];
  for (int c = t; c < C_NUM; c += 256) t1 += colsum[c];
  for (int c = t; c < C_NUM; c += 256) t2 += colsum[C_NUM + c];
  ce = block_reduce_256(ce, red);
  t1 = block_reduce_256(t1, red);
  t2 = block_reduce_256(t2, red);
  float e1 = 0.f, e2 = 0.f;
  for (int c = t; c < C_NUM; c += 256) {
    float m = colsum[c] / t1;
    e1 += m * logf(m);
  }
  for (int c = t; c < C_NUM; c += 256) {
    float m = colsum[C_NUM + c] / t2;
    e2 += m * logf(m);
  }
  e1 = block_reduce_256(e1, red);
  e2 = block_reduce_256(e2, red);
  if (t == 0) {
    float reg = logf((float)C_NUM) + e1 + logf((float)C_NUM) + e2;
    out[0] = ce / (float)N_TOT + reg;
  }
}

extern "C" void kernel_launch(void* const* d_in, const int* in_sizes, int n_in,
                              void* d_out, int out_size, void* d_ws, size_t ws_size,
                              hipStream_t stream) {
  const float* prob = (const float*)d_in[0];
  const float* prob_s = (const float*)d_in[1];
  float* out = (float*)d_out;

  char* ws = (char*)d_ws;
  unsigned short* Pn = (unsigned short*)ws;                     // 32 MB bf16
  float* norm2 = (float*)(ws + (size_t)N_TOT * B_TOT * 2);      // 4096 f32
  float* colsum = norm2 + N_TOT;                                // 4096 f32
  float* sumexp = colsum + N_TOT;                               // 4096 f32
  float* invn = sumexp + N_TOT;                                 // 4096 f32
  float* pos = invn + N_TOT;                                    // 4096 f32

  // zero the atomic accumulators (norm2, colsum, sumexp contiguous)
  hipMemsetAsync(norm2, 0, (size_t)3 * N_TOT * sizeof(float), stream);

  transpose_stats_kernel<<<dim3(64, 64), dim3(64, 4), 0, stream>>>(
      prob, prob_s, colsum, norm2, Pn);
  invnorm_kernel<<<16, 256, 0, stream>>>(norm2, invn);
  simgemm_kernel<<<528, 256, 0, stream>>>(Pn, invn, sumexp, pos);
  finalize_kernel<<<1, 256, 0, stream>>>(colsum, sumexp, pos, out);
}

// Round 3
// 146.329 us; speedup vs baseline: 1.8177x; 1.6426x over previous
//
#include <hip/hip_runtime.h>
#include <stdint.h>
#include <math.h>

#define C_NUM 2048
#define N_TOT 4096
#define B_TOT 4096
#define KNOWN 1024

typedef __attribute__((ext_vector_type(8))) short short8;
typedef __attribute__((ext_vector_type(4))) float f32x4;

__device__ __forceinline__ unsigned short f2bf(float x) {
  unsigned u = __float_as_uint(x);
  unsigned r = (u + 0x7fffu + ((u >> 16) & 1u)) >> 16;
  return (unsigned short)r;
}

__device__ __forceinline__ void gld16(const void* g, void* l) {
  __builtin_amdgcn_global_load_lds(
      (const __attribute__((address_space(1))) void*)g,
      (__attribute__((address_space(3))) void*)l, 16, 0, 0);
}

// ---- Kernel 1: transpose + bf16 convert + colsum/norm2 partials ----------
__global__ void transpose_stats_kernel(const float* __restrict__ prob,
                                       const float* __restrict__ prob_s,
                                       float* __restrict__ colsum,
                                       float* __restrict__ norm2,
                                       unsigned short* __restrict__ Pn) {
  __shared__ float tile[64][65];
  int tx = threadIdx.x;          // 0..63
  int ty = threadIdx.y;          // 0..3
  int c0 = blockIdx.x * 64;      // class tile (0..4095)
  int b0 = blockIdx.y * 64;      // batch tile
  const float* src = (c0 < C_NUM) ? prob : prob_s;
  int colbase = (c0 & (C_NUM - 1)) + tx;
  float s = 0.f, s2 = 0.f;
#pragma unroll
  for (int r = 0; r < 16; ++r) {
    int b = b0 + r * 4 + ty;
    float v = src[(size_t)b * C_NUM + colbase];
    tile[r * 4 + ty][tx] = v;
    s += v;
    s2 += v * v;
  }
  atomicAdd(&colsum[c0 + tx], s);
  atomicAdd(&norm2[c0 + tx], s2);
  __syncthreads();
#pragma unroll
  for (int r = 0; r < 16; ++r) {
    int i = c0 + r * 4 + ty;
    Pn[(size_t)i * B_TOT + b0 + tx] = f2bf(tile[tx][r * 4 + ty]);
  }
}

// ---- Kernel 2: invn[i] = 1/max(||P_i||, eps) ------------------------------
__global__ void invnorm_kernel(const float* __restrict__ norm2,
                               float* __restrict__ invn) {
  int i = blockIdx.x * 256 + threadIdx.x;
  invn[i] = 1.0f / fmaxf(sqrtf(norm2[i]), 1e-8f);
}

// ---- Kernel 3: symmetric fused GEMM + softmax-denominator epilogue -------
// Upper-triangular tile pairs (jt >= it), 128x128 tile, 512 threads = 8
// waves in a 2x4 grid; each wave owns a 64x32 sub-tile (4x2 fragments of
// 16x16x32 bf16 MFMA). Double-buffered LDS staged via global_load_lds.
__global__ __launch_bounds__(512) void simgemm_kernel(
    const unsigned short* __restrict__ Pn,
    const float* __restrict__ invn,
    float* __restrict__ sumexp,
    float* __restrict__ pos) {
  __shared__ unsigned short As[2][128 * 32];
  __shared__ unsigned short Bs[2][128 * 32];

  const int tid = threadIdx.x;
  const int l = tid & 63;
  const int w = tid >> 6;            // wave 0..7
  const int wr = w >> 2, wc = w & 3; // 2x4 wave grid

  // triangular decode: block t -> (it, jt) with jt >= it, 32x32 tile grid
  int t = blockIdx.x;
  int it = 0, rem = 32;
  while (t >= rem) { t -= rem; ++it; --rem; }
  const int jt = it + t;
  const int ib = it * 128;
  const int jb = jt * 128;
  const bool diag = (it == jt);

  // staging: thread tid covers 16B at LDS offset tid*16
  //   -> row = tid>>2 (0..127), kbyte = (tid&3)*16
  const int srow = tid >> 2;
  const int skb = (tid & 3) * 16;
  const char* gA = (const char*)Pn + (size_t)(ib + srow) * (B_TOT * 2) + skb;
  const char* gB = (const char*)Pn + (size_t)(jb + srow) * (B_TOT * 2) + skb;
  const int ldsOf = w * 1024 + l * 16;   // == tid*16

  f32x4 acc[4][2];
#pragma unroll
  for (int a = 0; a < 4; ++a)
#pragma unroll
    for (int b = 0; b < 2; ++b)
      acc[a][b] = (f32x4){0.f, 0.f, 0.f, 0.f};

  const int arow = wr * 64 + (l & 15);
  const int brow = wc * 32 + (l & 15);
  const int kb = (l >> 4) * 16;   // byte offset within 64B LDS k-row

#define STAGE(buf, kofs)                                  \
  do {                                                    \
    gld16(gA + (kofs), (char*)&As[buf][0] + ldsOf);       \
    gld16(gB + (kofs), (char*)&Bs[buf][0] + ldsOf);       \
  } while (0)

  STAGE(0, 0);
  __syncthreads();

  int cur = 0;
  const int NT = B_TOT / 32;   // 128 K-tiles
  for (int kt = 0; kt < NT; ++kt) {
    if (kt + 1 < NT) STAGE(cur ^ 1, (size_t)(kt + 1) * 64);

    short8 af[4], bf[2];
#pragma unroll
    for (int f = 0; f < 4; ++f)
      af[f] = *(const short8*)((const char*)&As[cur][0] + (arow + f * 16) * 64 + kb);
#pragma unroll
    for (int f = 0; f < 2; ++f)
      bf[f] = *(const short8*)((const char*)&Bs[cur][0] + (brow + f * 16) * 64 + kb);

#pragma unroll
    for (int fm = 0; fm < 4; ++fm)
#pragma unroll
      for (int fn = 0; fn < 2; ++fn)
        acc[fm][fn] = __builtin_amdgcn_mfma_f32_16x16x32_bf16(
            af[fm], bf[fn], acc[fm][fn], 0, 0, 0);

    __syncthreads();   // drains staging of next + LDS reads of cur
    cur ^= 1;
  }
#undef STAGE

  // epilogue. v = 2 * dot * invn[i] * invn[j]
  float invj[2];
#pragma unroll
  for (int fn = 0; fn < 2; ++fn)
    invj[fn] = invn[jb + wc * 32 + fn * 16 + (l & 15)];

  if (diag) {
#pragma unroll
    for (int fm = 0; fm < 4; ++fm) {
#pragma unroll
      for (int r = 0; r < 4; ++r) {
        const int i = ib + wr * 64 + fm * 16 + (l >> 4) * 4 + r;
        const float invi = invn[i];
        float rs = 0.f;
#pragma unroll
        for (int fn = 0; fn < 2; ++fn) {
          const int j = jb + wc * 32 + fn * 16 + (l & 15);
          float v = acc[fm][fn][r] * 2.0f * invi * invj[fn];
          if (j != i)   // i^2048 can't occur inside a diagonal block
            rs += (((i & 1024) == 0) && (j < KNOWN)) ? 1.0f : __expf(v);
        }
        rs += __shfl_xor(rs, 1);
        rs += __shfl_xor(rs, 2);
        rs += __shfl_xor(rs, 4);
        rs += __shfl_xor(rs, 8);
        if ((l & 15) == 0) atomicAdd(&sumexp[i], rs);
      }
    }
  } else {
    float cs[2] = {0.f, 0.f};   // per-fn contribution to column rows j
#pragma unroll
    for (int fm = 0; fm < 4; ++fm) {
#pragma unroll
      for (int r = 0; r < 4; ++r) {
        const int i = ib + wr * 64 + fm * 16 + (l >> 4) * 4 + r;
        const float invi = invn[i];
        float rs = 0.f;
#pragma unroll
        for (int fn = 0; fn < 2; ++fn) {
          const int j = jb + wc * 32 + fn * 16 + (l & 15);
          float v = acc[fm][fn][r] * 2.0f * invi * invj[fn];
          if (j == (i ^ 2048)) {
            pos[i] = v;          // symmetric entry has the same value
            pos[j] = v;
          } else {               // j != i always holds off-diagonal
            float e = __expf(v);
            rs += (((i & 1024) == 0) && (j < KNOWN)) ? 1.0f : e;
            cs[fn] += (((j & 1024) == 0) && (i < KNOWN)) ? 1.0f : e;
          }
        }
        rs += __shfl_xor(rs, 1);
        rs += __shfl_xor(rs, 2);
        rs += __shfl_xor(rs, 4);
        rs += __shfl_xor(rs, 8);
        if ((l & 15) == 0) atomicAdd(&sumexp[i], rs);
      }
    }
#pragma unroll
    for (int fn = 0; fn < 2; ++fn) {
      cs[fn] += __shfl_xor(cs[fn], 16);
      cs[fn] += __shfl_xor(cs[fn], 32);
    }
    if (l < 16) {
#pragma unroll
      for (int fn = 0; fn < 2; ++fn)
        atomicAdd(&sumexp[jb + wc * 32 + fn * 16 + l], cs[fn]);
    }
  }
}

// ---- Kernel 4: finalize ---------------------------------------------------
__device__ float block_reduce_256(float v, volatile float* red) {
#pragma unroll
  for (int m = 32; m >= 1; m >>= 1) v += __shfl_xor(v, m);
  __syncthreads();
  if ((threadIdx.x & 63) == 0) red[threadIdx.x >> 6] = v;
  __syncthreads();
  return red[0] + red[1] + red[2] + red[3];
}

__global__ void finalize_kernel(const float* __restrict__ colsum,
                                const float* __restrict__ sumexp,
                                const float* __restrict__ pos,
                                float* __restrict__ out) {
  __shared__ float red[4];
  int t = threadIdx.x;
  float ce = 0.f, t1 = 0.f, t2 = 0.f;
  for (int i = t; i < N_TOT; i += 256) ce += logf(sumexp[i]) - pos[i];
  for (int c = t; c < C_NUM; c += 256) t1 += colsum[c];
  for (int c = t; c < C_NUM; c += 256) t2 += colsum[C_NUM + c];
  ce = block_reduce_256(ce, red);
  t1 = block_reduce_256(t1, red);
  t2 = block_reduce_256(t2, red);
  float e1 = 0.f, e2 = 0.f;
  for (int c = t; c < C_NUM; c += 256) {
    float m = colsum[c] / t1;
    e1 += m * logf(m);
  }
  for (int c = t; c < C_NUM; c += 256) {
    float m = colsum[C_NUM + c] / t2;
    e2 += m * logf(m);
  }
  e1 = block_reduce_256(e1, red);
  e2 = block_reduce_256(e2, red);
  if (t == 0) {
    float reg = logf((float)C_NUM) + e1 + logf((float)C_NUM) + e2;
    out[0] = ce / (float)N_TOT + reg;
  }
}

extern "C" void kernel_launch(void* const* d_in, const int* in_sizes, int n_in,
                              void* d_out, int out_size, void* d_ws, size_t ws_size,
                              hipStream_t stream) {
  const float* prob = (const float*)d_in[0];
  const float* prob_s = (const float*)d_in[1];
  float* out = (float*)d_out;

  char* ws = (char*)d_ws;
  unsigned short* Pn = (unsigned short*)ws;                     // 32 MB bf16
  float* norm2 = (float*)(ws + (size_t)N_TOT * B_TOT * 2);      // 4096 f32
  float* colsum = norm2 + N_TOT;                                // 4096 f32
  float* sumexp = colsum + N_TOT;                               // 4096 f32
  float* invn = sumexp + N_TOT;                                 // 4096 f32
  float* pos = invn + N_TOT;                                    // 4096 f32

  // zero the atomic accumulators (norm2, colsum, sumexp contiguous)
  hipMemsetAsync(norm2, 0, (size_t)3 * N_TOT * sizeof(float), stream);

  transpose_stats_kernel<<<dim3(64, 64), dim3(64, 4), 0, stream>>>(
      prob, prob_s, colsum, norm2, Pn);
  invnorm_kernel<<<16, 256, 0, stream>>>(norm2, invn);
  simgemm_kernel<<<528, 512, 0, stream>>>(Pn, invn, sumexp, pos);
  finalize_kernel<<<1, 256, 0, stream>>>(colsum, sumexp, pos, out);
}